// Round 2
// baseline (3906.828 us; speedup 1.0000x reference)
//
#include <hip/hip_runtime.h>
#include <cstddef>

// LocalGOCorrOpt on MI355X — round 2: occupancy fix.
// Block = 256 threads (4 waves) per (b,y) pixel-row; wave w owns channel-quads
// [w*16, w*16+16). Cross-wave reduce of 81-vectors via chunked LDS (conflict-free
// lane-stride-1). t2 reuses sacc registers -> VGPR <= 128 -> 4 blocks/CU.
// XCD-bijective swizzle: 1024 blocks % 8 == 0.

#define FPL 4096   // 64*64 floats per f channel-plane
#define RPQ 20736  // 72*72*4 floats per rpad c4-plane
#define GPQ 16384  // 64*64*4 floats per gbuf c4-plane

// ---------------- constants kernel ----------------
__global__ void k_consts(const float* lsl, const float* freg, const float* lw,
                         const float* sw, const float* mw, float* ws) {
  int t = threadIdx.x;
  if (t < 81) {
    int dy = t / 9, dx = t % 9;
    float ky = (float)(dy - 4), kx = (float)(dx - 4);
    float dist = sqrtf(ky * ky + kx * kx);
    float tg = 0.f, vp = 0.f, z = 0.f;
    for (int k = 0; k < 10; ++k) {
      float bd = 2.f * dist - (float)k;               // dist/0.5 - k
      float bin = (k < 9) ? fmaxf(1.f - fabsf(bd), 0.f)
                          : fminf(fmaxf(1.f + bd, 0.f), 1.f);
      tg += lw[k] * bin; vp += sw[k] * bin; z += mw[k] * bin;
    }
    ws[t] = tg;                      // target_map
    ws[81 + t] = vp;                 // v_plus
    ws[162 + t] = 1.f / (1.f + expf(-z));  // weight_m (sigmoid)
  } else if (t == 81) {
    float fr = freg[0];
    ws[243] = fmaxf(fr * fr, 1e-10f) * (1.f / 65536.f);  // reg_weight
  } else if (t == 82) {
    ws[244] = expf(lsl[0]);          // step_length
  }
}

// ---------------- r repack: NCHW -> padded channel-quad ----------------
__global__ void k_pad(const float* __restrict__ r, float* __restrict__ rp) {
  size_t i = (size_t)blockIdx.x * 256 + threadIdx.x;
  const size_t N = (size_t)16 * 64 * 72 * 72 * 4;
  if (i >= N) return;
  int j = (int)(i & 3);
  size_t qi = i >> 2;
  int col = (int)(qi % 72); size_t t1 = qi / 72;
  int row = (int)(t1 % 72); size_t t2 = t1 / 72;
  int c4 = (int)(t2 % 64);  int b  = (int)(t2 / 64);
  int yy = row - 4, xx = col - 4;
  float v = 0.f;
  if ((unsigned)yy < 64u && (unsigned)xx < 64u)
    v = r[(((size_t)b * 256 + (size_t)(c4 * 4 + j)) * 64 + yy) * 64 + xx];
  rp[i] = v;
}

// ---------------- fused single-iteration kernel (4-wave version) ----------------
__global__ __launch_bounds__(256, 4) void k_iterB(
    const float* fin, const float* __restrict__ rp,
    const float* __restrict__ cst, float* __restrict__ gbuf, float* fout) {
  // XCD-bijective swizzle: 1024 workgroups, 8 XCDs -> 128 contiguous per XCD.
  const int wg = blockIdx.x;
  const int swz = (wg & 7) * 128 + (wg >> 3);
  const int b = swz >> 6, y = swz & 63;
  const int tid = threadIdx.x;
  const int w = tid >> 6;          // wave 0..3
  const int x = tid & 63;          // pixel column
  const int c4lo = w * 16;
  const float rw = cst[243], step = cst[244];

  const float* fbase = fin + (size_t)b * 256 * FPL + (size_t)y * 64 + x;
  const float* rbase = rp + (size_t)b * 64 * RPQ + ((size_t)y * 72 + x) * 4;
  float* gb = gbuf + (size_t)b * 64 * GPQ + ((size_t)y * 64 + x) * 4;

  __shared__ float red[4][27][64];   // 27648 B, lane-stride-1 -> conflict-free
  __shared__ float nbuf[4][64];      // 1024 B

  // ---- P1: partial scores over this wave's 16 channel-quads ----
  float sacc[81];
#pragma unroll
  for (int d = 0; d < 81; ++d) sacc[d] = 0.f;
  for (int c4 = c4lo; c4 < c4lo + 16; ++c4) {
    const float* fc = fbase + (size_t)c4 * 4 * FPL;
    float f0 = fc[0], f1 = fc[FPL], f2 = fc[2 * FPL], f3 = fc[3 * FPL];
    const float* rc = rbase + (size_t)c4 * RPQ;
#pragma unroll
    for (int dy = 0; dy < 9; ++dy) {
#pragma unroll
      for (int dx = 0; dx < 9; ++dx) {
        float4 rv = *(const float4*)(rc + (size_t)(dy * 72 + dx) * 4);
        float a = sacc[dy * 9 + dx];
        a = fmaf(f0, rv.x, a); a = fmaf(f1, rv.y, a);
        a = fmaf(f2, rv.z, a); a = fmaf(f3, rv.w, a);
        sacc[dy * 9 + dx] = a;
      }
    }
  }
  // cross-wave reduce scores (3 chunks of 27)
#pragma unroll
  for (int q = 0; q < 3; ++q) {
#pragma unroll
    for (int j = 0; j < 27; ++j) red[w][j][x] = sacc[q * 27 + j];
    __syncthreads();
#pragma unroll
    for (int j = 0; j < 27; ++j)
      sacc[q * 27 + j] = (red[0][j][x] + red[1][j][x]) + (red[2][j][x] + red[3][j][x]);
    __syncthreads();
  }

  // ---- P2: mapped (in place) + sign masks (redundant per wave) ----
  unsigned pm[3] = {0u, 0u, 0u}, nm[3] = {0u, 0u, 0u};
#pragma unroll
  for (int d = 0; d < 81; ++d) {
    float s = sacc[d];
    float tg = cst[d], vp = cst[81 + d], wm = cst[162 + d];
    float ga = vp * (s > 0.f ? 1.f : (s < 0.f ? wm : 0.5f * (1.f + wm)));
    sacc[d] = ga * fmaf(ga, s, -(vp * tg));   // mapped
    pm[d / 27] |= (s > 0.f ? 1u : 0u) << (d % 27);
    nm[d / 27] |= (s < 0.f ? 1u : 0u) << (d % 27);
  }

  // ---- P3a: g = rw*f + R*mapped over own c4s; spill to gbuf; partial |g|^2 ----
  float npart = 0.f;
  for (int c4 = c4lo; c4 < c4lo + 16; ++c4) {
    const float* fc = fbase + (size_t)c4 * 4 * FPL;
    const float* rc = rbase + (size_t)c4 * RPQ;
    float g0 = 0.f, g1 = 0.f, g2 = 0.f, g3 = 0.f;
#pragma unroll
    for (int dy = 0; dy < 9; ++dy) {
#pragma unroll
      for (int dx = 0; dx < 9; ++dx) {
        float4 rv = *(const float4*)(rc + (size_t)(dy * 72 + dx) * 4);
        float mv = sacc[dy * 9 + dx];
        g0 = fmaf(mv, rv.x, g0); g1 = fmaf(mv, rv.y, g1);
        g2 = fmaf(mv, rv.z, g2); g3 = fmaf(mv, rv.w, g3);
      }
    }
    g0 = fmaf(rw, fc[0], g0);       g1 = fmaf(rw, fc[FPL], g1);
    g2 = fmaf(rw, fc[2 * FPL], g2); g3 = fmaf(rw, fc[3 * FPL], g3);
    float4 g4; g4.x = g0; g4.y = g1; g4.z = g2; g4.w = g3;
    *(float4*)(gb + (size_t)c4 * GPQ) = g4;
    npart = fmaf(g0, g0, npart); npart = fmaf(g1, g1, npart);
    npart = fmaf(g2, g2, npart); npart = fmaf(g3, g3, npart);
  }
  nbuf[w][x] = npart;
  __syncthreads();
  const float num = (nbuf[0][x] + nbuf[1][x]) + (nbuf[2][x] + nbuf[3][x]);

  // ---- P3b: t2 partial over own c4s (t2 reuses sacc; mapped is dead) ----
#pragma unroll
  for (int d = 0; d < 81; ++d) sacc[d] = 0.f;
  for (int c4 = c4lo; c4 < c4lo + 16; ++c4) {
    const float* rc = rbase + (size_t)c4 * RPQ;
    float4 g4 = *(const float4*)(gb + (size_t)c4 * GPQ);
#pragma unroll
    for (int dy = 0; dy < 9; ++dy) {
#pragma unroll
      for (int dx = 0; dx < 9; ++dx) {
        float4 rv = *(const float4*)(rc + (size_t)(dy * 72 + dx) * 4);
        float a = sacc[dy * 9 + dx];
        a = fmaf(g4.x, rv.x, a); a = fmaf(g4.y, rv.y, a);
        a = fmaf(g4.z, rv.z, a); a = fmaf(g4.w, rv.w, a);
        sacc[dy * 9 + dx] = a;
      }
    }
  }
  // cross-wave reduce t2 (reuse red; last use was before the barrier above)
#pragma unroll
  for (int q = 0; q < 3; ++q) {
    __syncthreads();
#pragma unroll
    for (int j = 0; j < 27; ++j) red[w][j][x] = sacc[q * 27 + j];
    __syncthreads();
#pragma unroll
    for (int j = 0; j < 27; ++j)
      sacc[q * 27 + j] = (red[0][j][x] + red[1][j][x]) + (red[2][j][x] + red[3][j][x]);
  }

  // ---- P4: den, coef (redundant per wave) ----
  float den = 0.f;
#pragma unroll
  for (int d = 0; d < 81; ++d) {
    float vp = cst[81 + d], wm = cst[162 + d];
    unsigned p = (pm[d / 27] >> (d % 27)) & 1u;
    unsigned n = (nm[d / 27] >> (d % 27)) & 1u;
    float ga = vp * (p ? 1.f : (n ? wm : 0.5f * (1.f + wm)));
    float s2 = ga * sacc[d];
    den = fmaf(s2, s2, den);
  }
  den = fmaxf(fmaf(rw, num, den), 1e-8f);
  const float coef = step * num / den;

  // ---- P5: f_new = f - coef*g over own c4s ----
  float* ob = fout + (size_t)b * 256 * FPL + (size_t)y * 64 + x;
  for (int c4 = c4lo; c4 < c4lo + 16; ++c4) {
    const float* fc = fbase + (size_t)c4 * 4 * FPL;
    float4 g4 = *(const float4*)(gb + (size_t)c4 * GPQ);
    size_t o = (size_t)c4 * 4 * FPL;
    ob[o]           = fmaf(-coef, g4.x, fc[0]);
    ob[o + FPL]     = fmaf(-coef, g4.y, fc[FPL]);
    ob[o + 2 * FPL] = fmaf(-coef, g4.z, fc[2 * FPL]);
    ob[o + 3 * FPL] = fmaf(-coef, g4.w, fc[3 * FPL]);
  }
}

// ---------------- fallback: self-contained, no workspace needed ----------------
__device__ __forceinline__ void consts_d(int d, const float* lwr, const float* swr,
                                         const float* mwr, float& tg, float& vp,
                                         float& wm) {
  int dy = d / 9, dx = d % 9;
  float ky = (float)(dy - 4), kx = (float)(dx - 4);
  float dist = sqrtf(ky * ky + kx * kx);
  float t = 0.f, v = 0.f, z = 0.f;
#pragma unroll
  for (int k = 0; k < 10; ++k) {
    float bd = 2.f * dist - (float)k;
    float bin = (k < 9) ? fmaxf(1.f - fabsf(bd), 0.f)
                        : fminf(fmaxf(1.f + bd, 0.f), 1.f);
    t = fmaf(lwr[k], bin, t); v = fmaf(swr[k], bin, v); z = fmaf(mwr[k], bin, z);
  }
  tg = t; vp = v; wm = 1.f / (1.f + expf(-z));
}

__global__ __launch_bounds__(64, 1) void k_iterC(
    const float* fin, const float* __restrict__ r, const float* __restrict__ lsl,
    const float* __restrict__ freg, const float* __restrict__ lw,
    const float* __restrict__ sw, const float* __restrict__ mw, float* fout) {
  const int b = blockIdx.x >> 6, y = blockIdx.x & 63;
  const int x = threadIdx.x;
  float lwr[10], swr[10], mwr[10];
#pragma unroll
  for (int k = 0; k < 10; ++k) { lwr[k] = lw[k]; swr[k] = sw[k]; mwr[k] = mw[k]; }
  float fr = freg[0];
  const float rw = fmaxf(fr * fr, 1e-10f) * (1.f / 65536.f);
  const float step = expf(lsl[0]);
  const float* fb = fin + (size_t)b * 256 * FPL + (size_t)y * 64 + x;
  const float* rb = r + (size_t)b * 256 * FPL;

  float m[81];
#pragma unroll
  for (int d = 0; d < 81; ++d) m[d] = 0.f;
  for (int c = 0; c < 256; ++c) {
    float fv = fb[(size_t)c * FPL];
    const float* rc = rb + (size_t)c * FPL;
#pragma unroll
    for (int dy = 0; dy < 9; ++dy) {
      int yy = y + dy - 4;
      if ((unsigned)yy < 64u) {
        const float* rrow = rc + yy * 64;
#pragma unroll
        for (int dx = 0; dx < 9; ++dx) {
          int xx = x + dx - 4;
          float rv = ((unsigned)xx < 64u) ? rrow[xx] : 0.f;
          m[dy * 9 + dx] = fmaf(fv, rv, m[dy * 9 + dx]);
        }
      }
    }
  }
  unsigned pm[3] = {0u, 0u, 0u}, nm[3] = {0u, 0u, 0u};
#pragma unroll
  for (int d = 0; d < 81; ++d) {
    float tg, vp, wm; consts_d(d, lwr, swr, mwr, tg, vp, wm);
    float s = m[d];
    float ga = vp * (s > 0.f ? 1.f : (s < 0.f ? wm : 0.5f * (1.f + wm)));
    m[d] = ga * fmaf(ga, s, -(vp * tg));
    pm[d / 27] |= (s > 0.f ? 1u : 0u) << (d % 27);
    nm[d / 27] |= (s < 0.f ? 1u : 0u) << (d % 27);
  }
  float t2[81];
#pragma unroll
  for (int d = 0; d < 81; ++d) t2[d] = 0.f;
  float num = 0.f;
  for (int c = 0; c < 256; ++c) {
    float fv = fb[(size_t)c * FPL];
    const float* rc = rb + (size_t)c * FPL;
    float g0 = 0.f, g1 = 0.f, g2 = 0.f, g3 = 0.f;
#pragma unroll
    for (int dy = 0; dy < 9; ++dy) {
      int yy = y + dy - 4;
      if ((unsigned)yy < 64u) {
        const float* rrow = rc + yy * 64;
#pragma unroll
        for (int dx = 0; dx < 9; ++dx) {
          int xx = x + dx - 4;
          float rv = ((unsigned)xx < 64u) ? rrow[xx] : 0.f;
          if ((dy & 3) == 0)      g0 = fmaf(m[dy * 9 + dx], rv, g0);
          else if ((dy & 3) == 1) g1 = fmaf(m[dy * 9 + dx], rv, g1);
          else if ((dy & 3) == 2) g2 = fmaf(m[dy * 9 + dx], rv, g2);
          else                    g3 = fmaf(m[dy * 9 + dx], rv, g3);
        }
      }
    }
    float g = fmaf(rw, fv, (g0 + g1) + (g2 + g3));
    num = fmaf(g, g, num);
#pragma unroll
    for (int dy = 0; dy < 9; ++dy) {
      int yy = y + dy - 4;
      if ((unsigned)yy < 64u) {
        const float* rrow = rc + yy * 64;
#pragma unroll
        for (int dx = 0; dx < 9; ++dx) {
          int xx = x + dx - 4;
          float rv = ((unsigned)xx < 64u) ? rrow[xx] : 0.f;
          t2[dy * 9 + dx] = fmaf(g, rv, t2[dy * 9 + dx]);
        }
      }
    }
  }
  float den = 0.f;
#pragma unroll
  for (int d = 0; d < 81; ++d) {
    float tg, vp, wm; consts_d(d, lwr, swr, mwr, tg, vp, wm);
    (void)tg;
    unsigned p = (pm[d / 27] >> (d % 27)) & 1u;
    unsigned n = (nm[d / 27] >> (d % 27)) & 1u;
    float ga = vp * (p ? 1.f : (n ? wm : 0.5f * (1.f + wm)));
    float s2 = ga * t2[d];
    den = fmaf(s2, s2, den);
  }
  den = fmaxf(fmaf(rw, num, den), 1e-8f);
  float coef = step * num / den;
  float* ob = fout + (size_t)b * 256 * FPL + (size_t)y * 64 + x;
  for (int c = 0; c < 256; ++c) {
    float fv = fb[(size_t)c * FPL];
    const float* rc = rb + (size_t)c * FPL;
    float g0 = 0.f, g1 = 0.f, g2 = 0.f, g3 = 0.f;
#pragma unroll
    for (int dy = 0; dy < 9; ++dy) {
      int yy = y + dy - 4;
      if ((unsigned)yy < 64u) {
        const float* rrow = rc + yy * 64;
#pragma unroll
        for (int dx = 0; dx < 9; ++dx) {
          int xx = x + dx - 4;
          float rv = ((unsigned)xx < 64u) ? rrow[xx] : 0.f;
          if ((dy & 3) == 0)      g0 = fmaf(m[dy * 9 + dx], rv, g0);
          else if ((dy & 3) == 1) g1 = fmaf(m[dy * 9 + dx], rv, g1);
          else if ((dy & 3) == 2) g2 = fmaf(m[dy * 9 + dx], rv, g2);
          else                    g3 = fmaf(m[dy * 9 + dx], rv, g3);
        }
      }
    }
    float g = fmaf(rw, fv, (g0 + g1) + (g2 + g3));
    ob[(size_t)c * FPL] = fmaf(-coef, g, fv);
  }
}

extern "C" void kernel_launch(void* const* d_in, const int* in_sizes, int n_in,
                              void* d_out, int out_size, void* d_ws, size_t ws_size,
                              hipStream_t stream) {
  (void)in_sizes; (void)n_in; (void)out_size;
  const float* f0 = (const float*)d_in[0];
  const float* r  = (const float*)d_in[1];
  const float* lsl = (const float*)d_in[2];
  const float* freg = (const float*)d_in[3];
  const float* lw = (const float*)d_in[4];
  const float* sw = (const float*)d_in[5];
  const float* mw = (const float*)d_in[6];
  float* out = (float*)d_out;

  const size_t CONSTS = 256;
  const size_t GSZ = (size_t)16 * 256 * 64 * 64;     // gbuf floats
  const size_t RPSZ = (size_t)16 * 64 * 72 * 72 * 4; // rpad floats
  const size_t needed = (CONSTS + GSZ + RPSZ) * sizeof(float);

  if (ws_size >= needed) {
    float* ws = (float*)d_ws;
    float* gbuf = ws + CONSTS;
    float* rpad = gbuf + GSZ;
    k_consts<<<dim3(1), dim3(128), 0, stream>>>(lsl, freg, lw, sw, mw, ws);
    k_pad<<<dim3((unsigned)((RPSZ + 255) / 256)), dim3(256), 0, stream>>>(r, rpad);
    k_iterB<<<dim3(1024), dim3(256), 0, stream>>>(f0, rpad, ws, gbuf, out);
    k_iterB<<<dim3(1024), dim3(256), 0, stream>>>(out, rpad, ws, gbuf, out);
    k_iterB<<<dim3(1024), dim3(256), 0, stream>>>(out, rpad, ws, gbuf, out);
  } else {
    k_iterC<<<dim3(1024), dim3(64), 0, stream>>>(f0, r, lsl, freg, lw, sw, mw, out);
    k_iterC<<<dim3(1024), dim3(64), 0, stream>>>(out, r, lsl, freg, lw, sw, mw, out);
    k_iterC<<<dim3(1024), dim3(64), 0, stream>>>(out, r, lsl, freg, lw, sw, mw, out);
  }
}

// Round 4
// 2891.743 us; speedup vs baseline: 1.3510x; 1.3510x over previous
//
#include <hip/hip_runtime.h>
#include <cstddef>

// LocalGOCorrOpt on MI355X — round 4: resubmit of round 3 (bench never ran:
// GPU acquisition timeout). Fix for round-2 spill: launch_bounds(256,2) caps
// VGPR at 128 >= ~115 live set -> no scratch; still 16 waves/CU.
// Block = 256 threads (4 waves) per (b,y) row; wave w owns channel-quads
// [w*16, w*16+16); cross-wave 81-vector reduce via chunked LDS.

#define FPL 4096   // 64*64 floats per f channel-plane
#define RPQ 20736  // 72*72*4 floats per rpad c4-plane
#define GPQ 16384  // 64*64*4 floats per gbuf c4-plane

// ---------------- constants kernel ----------------
__global__ void k_consts(const float* lsl, const float* freg, const float* lw,
                         const float* sw, const float* mw, float* ws) {
  int t = threadIdx.x;
  if (t < 81) {
    int dy = t / 9, dx = t % 9;
    float ky = (float)(dy - 4), kx = (float)(dx - 4);
    float dist = sqrtf(ky * ky + kx * kx);
    float tg = 0.f, vp = 0.f, z = 0.f;
    for (int k = 0; k < 10; ++k) {
      float bd = 2.f * dist - (float)k;               // dist/0.5 - k
      float bin = (k < 9) ? fmaxf(1.f - fabsf(bd), 0.f)
                          : fminf(fmaxf(1.f + bd, 0.f), 1.f);
      tg += lw[k] * bin; vp += sw[k] * bin; z += mw[k] * bin;
    }
    ws[t] = tg;                      // target_map
    ws[81 + t] = vp;                 // v_plus
    ws[162 + t] = 1.f / (1.f + expf(-z));  // weight_m (sigmoid)
  } else if (t == 81) {
    float fr = freg[0];
    ws[243] = fmaxf(fr * fr, 1e-10f) * (1.f / 65536.f);  // reg_weight
  } else if (t == 82) {
    ws[244] = expf(lsl[0]);          // step_length
  }
}

// ---------------- r repack: NCHW -> padded channel-quad ----------------
__global__ void k_pad(const float* __restrict__ r, float* __restrict__ rp) {
  size_t i = (size_t)blockIdx.x * 256 + threadIdx.x;
  const size_t N = (size_t)16 * 64 * 72 * 72 * 4;
  if (i >= N) return;
  int j = (int)(i & 3);
  size_t qi = i >> 2;
  int col = (int)(qi % 72); size_t t1 = qi / 72;
  int row = (int)(t1 % 72); size_t t2 = t1 / 72;
  int c4 = (int)(t2 % 64);  int b  = (int)(t2 / 64);
  int yy = row - 4, xx = col - 4;
  float v = 0.f;
  if ((unsigned)yy < 64u && (unsigned)xx < 64u)
    v = r[(((size_t)b * 256 + (size_t)(c4 * 4 + j)) * 64 + yy) * 64 + xx];
  rp[i] = v;
}

// ---------------- fused single-iteration kernel (4-wave version) ----------------
__global__ __launch_bounds__(256, 2) void k_iterB(
    const float* fin, const float* __restrict__ rp,
    const float* __restrict__ cst, float* __restrict__ gbuf, float* fout) {
  // XCD-bijective swizzle: 1024 workgroups, 8 XCDs -> 128 contiguous per XCD.
  const int wg = blockIdx.x;
  const int swz = (wg & 7) * 128 + (wg >> 3);
  const int b = swz >> 6, y = swz & 63;
  const int tid = threadIdx.x;
  const int w = tid >> 6;          // wave 0..3
  const int x = tid & 63;          // pixel column
  const int c4lo = w * 16;
  const float rw = cst[243], step = cst[244];

  const float* fbase = fin + (size_t)b * 256 * FPL + (size_t)y * 64 + x;
  const float* rbase = rp + (size_t)b * 64 * RPQ + ((size_t)y * 72 + x) * 4;
  float* gb = gbuf + (size_t)b * 64 * GPQ + ((size_t)y * 64 + x) * 4;

  __shared__ float red[4][27][64];   // 27648 B, lane-stride-1 -> conflict-free
  __shared__ float nbuf[4][64];      // 1024 B

  // ---- P1: partial scores over this wave's 16 channel-quads ----
  float sacc[81];
#pragma unroll
  for (int d = 0; d < 81; ++d) sacc[d] = 0.f;
  for (int c4 = c4lo; c4 < c4lo + 16; ++c4) {
    const float* fc = fbase + (size_t)c4 * 4 * FPL;
    float f0 = fc[0], f1 = fc[FPL], f2 = fc[2 * FPL], f3 = fc[3 * FPL];
    const float* rc = rbase + (size_t)c4 * RPQ;
#pragma unroll
    for (int dy = 0; dy < 9; ++dy) {
#pragma unroll
      for (int dx = 0; dx < 9; ++dx) {
        float4 rv = *(const float4*)(rc + (size_t)(dy * 72 + dx) * 4);
        float a = sacc[dy * 9 + dx];
        a = fmaf(f0, rv.x, a); a = fmaf(f1, rv.y, a);
        a = fmaf(f2, rv.z, a); a = fmaf(f3, rv.w, a);
        sacc[dy * 9 + dx] = a;
      }
    }
  }
  // cross-wave reduce scores (3 chunks of 27)
#pragma unroll
  for (int q = 0; q < 3; ++q) {
#pragma unroll
    for (int j = 0; j < 27; ++j) red[w][j][x] = sacc[q * 27 + j];
    __syncthreads();
#pragma unroll
    for (int j = 0; j < 27; ++j)
      sacc[q * 27 + j] = (red[0][j][x] + red[1][j][x]) + (red[2][j][x] + red[3][j][x]);
    __syncthreads();
  }

  // ---- P2: mapped (in place) + sign masks (redundant per wave) ----
  unsigned pm[3] = {0u, 0u, 0u}, nm[3] = {0u, 0u, 0u};
#pragma unroll
  for (int d = 0; d < 81; ++d) {
    float s = sacc[d];
    float tg = cst[d], vp = cst[81 + d], wm = cst[162 + d];
    float ga = vp * (s > 0.f ? 1.f : (s < 0.f ? wm : 0.5f * (1.f + wm)));
    sacc[d] = ga * fmaf(ga, s, -(vp * tg));   // mapped
    pm[d / 27] |= (s > 0.f ? 1u : 0u) << (d % 27);
    nm[d / 27] |= (s < 0.f ? 1u : 0u) << (d % 27);
  }

  // ---- P3a: g = rw*f + R*mapped over own c4s; spill to gbuf; partial |g|^2 ----
  float npart = 0.f;
  for (int c4 = c4lo; c4 < c4lo + 16; ++c4) {
    const float* fc = fbase + (size_t)c4 * 4 * FPL;
    const float* rc = rbase + (size_t)c4 * RPQ;
    float g0 = 0.f, g1 = 0.f, g2 = 0.f, g3 = 0.f;
#pragma unroll
    for (int dy = 0; dy < 9; ++dy) {
#pragma unroll
      for (int dx = 0; dx < 9; ++dx) {
        float4 rv = *(const float4*)(rc + (size_t)(dy * 72 + dx) * 4);
        float mv = sacc[dy * 9 + dx];
        g0 = fmaf(mv, rv.x, g0); g1 = fmaf(mv, rv.y, g1);
        g2 = fmaf(mv, rv.z, g2); g3 = fmaf(mv, rv.w, g3);
      }
    }
    g0 = fmaf(rw, fc[0], g0);       g1 = fmaf(rw, fc[FPL], g1);
    g2 = fmaf(rw, fc[2 * FPL], g2); g3 = fmaf(rw, fc[3 * FPL], g3);
    float4 g4; g4.x = g0; g4.y = g1; g4.z = g2; g4.w = g3;
    *(float4*)(gb + (size_t)c4 * GPQ) = g4;
    npart = fmaf(g0, g0, npart); npart = fmaf(g1, g1, npart);
    npart = fmaf(g2, g2, npart); npart = fmaf(g3, g3, npart);
  }
  nbuf[w][x] = npart;
  __syncthreads();
  const float num = (nbuf[0][x] + nbuf[1][x]) + (nbuf[2][x] + nbuf[3][x]);

  // ---- P3b: t2 partial over own c4s (t2 reuses sacc; mapped is dead) ----
#pragma unroll
  for (int d = 0; d < 81; ++d) sacc[d] = 0.f;
  for (int c4 = c4lo; c4 < c4lo + 16; ++c4) {
    const float* rc = rbase + (size_t)c4 * RPQ;
    float4 g4 = *(const float4*)(gb + (size_t)c4 * GPQ);
#pragma unroll
    for (int dy = 0; dy < 9; ++dy) {
#pragma unroll
      for (int dx = 0; dx < 9; ++dx) {
        float4 rv = *(const float4*)(rc + (size_t)(dy * 72 + dx) * 4);
        float a = sacc[dy * 9 + dx];
        a = fmaf(g4.x, rv.x, a); a = fmaf(g4.y, rv.y, a);
        a = fmaf(g4.z, rv.z, a); a = fmaf(g4.w, rv.w, a);
        sacc[dy * 9 + dx] = a;
      }
    }
  }
  // cross-wave reduce t2 (reuse red)
#pragma unroll
  for (int q = 0; q < 3; ++q) {
    __syncthreads();
#pragma unroll
    for (int j = 0; j < 27; ++j) red[w][j][x] = sacc[q * 27 + j];
    __syncthreads();
#pragma unroll
    for (int j = 0; j < 27; ++j)
      sacc[q * 27 + j] = (red[0][j][x] + red[1][j][x]) + (red[2][j][x] + red[3][j][x]);
  }

  // ---- P4: den, coef (redundant per wave) ----
  float den = 0.f;
#pragma unroll
  for (int d = 0; d < 81; ++d) {
    float vp = cst[81 + d], wm = cst[162 + d];
    unsigned p = (pm[d / 27] >> (d % 27)) & 1u;
    unsigned n = (nm[d / 27] >> (d % 27)) & 1u;
    float ga = vp * (p ? 1.f : (n ? wm : 0.5f * (1.f + wm)));
    float s2 = ga * sacc[d];
    den = fmaf(s2, s2, den);
  }
  den = fmaxf(fmaf(rw, num, den), 1e-8f);
  const float coef = step * num / den;

  // ---- P5: f_new = f - coef*g over own c4s ----
  float* ob = fout + (size_t)b * 256 * FPL + (size_t)y * 64 + x;
  for (int c4 = c4lo; c4 < c4lo + 16; ++c4) {
    const float* fc = fbase + (size_t)c4 * 4 * FPL;
    float4 g4 = *(const float4*)(gb + (size_t)c4 * GPQ);
    size_t o = (size_t)c4 * 4 * FPL;
    ob[o]           = fmaf(-coef, g4.x, fc[0]);
    ob[o + FPL]     = fmaf(-coef, g4.y, fc[FPL]);
    ob[o + 2 * FPL] = fmaf(-coef, g4.z, fc[2 * FPL]);
    ob[o + 3 * FPL] = fmaf(-coef, g4.w, fc[3 * FPL]);
  }
}

// ---------------- fallback: self-contained, no workspace needed ----------------
__device__ __forceinline__ void consts_d(int d, const float* lwr, const float* swr,
                                         const float* mwr, float& tg, float& vp,
                                         float& wm) {
  int dy = d / 9, dx = d % 9;
  float ky = (float)(dy - 4), kx = (float)(dx - 4);
  float dist = sqrtf(ky * ky + kx * kx);
  float t = 0.f, v = 0.f, z = 0.f;
#pragma unroll
  for (int k = 0; k < 10; ++k) {
    float bd = 2.f * dist - (float)k;
    float bin = (k < 9) ? fmaxf(1.f - fabsf(bd), 0.f)
                        : fminf(fmaxf(1.f + bd, 0.f), 1.f);
    t = fmaf(lwr[k], bin, t); v = fmaf(swr[k], bin, v); z = fmaf(mwr[k], bin, z);
  }
  tg = t; vp = v; wm = 1.f / (1.f + expf(-z));
}

__global__ __launch_bounds__(64, 1) void k_iterC(
    const float* fin, const float* __restrict__ r, const float* __restrict__ lsl,
    const float* __restrict__ freg, const float* __restrict__ lw,
    const float* __restrict__ sw, const float* __restrict__ mw, float* fout) {
  const int b = blockIdx.x >> 6, y = blockIdx.x & 63;
  const int x = threadIdx.x;
  float lwr[10], swr[10], mwr[10];
#pragma unroll
  for (int k = 0; k < 10; ++k) { lwr[k] = lw[k]; swr[k] = sw[k]; mwr[k] = mw[k]; }
  float fr = freg[0];
  const float rw = fmaxf(fr * fr, 1e-10f) * (1.f / 65536.f);
  const float step = expf(lsl[0]);
  const float* fb = fin + (size_t)b * 256 * FPL + (size_t)y * 64 + x;
  const float* rb = r + (size_t)b * 256 * FPL;

  float m[81];
#pragma unroll
  for (int d = 0; d < 81; ++d) m[d] = 0.f;
  for (int c = 0; c < 256; ++c) {
    float fv = fb[(size_t)c * FPL];
    const float* rc = rb + (size_t)c * FPL;
#pragma unroll
    for (int dy = 0; dy < 9; ++dy) {
      int yy = y + dy - 4;
      if ((unsigned)yy < 64u) {
        const float* rrow = rc + yy * 64;
#pragma unroll
        for (int dx = 0; dx < 9; ++dx) {
          int xx = x + dx - 4;
          float rv = ((unsigned)xx < 64u) ? rrow[xx] : 0.f;
          m[dy * 9 + dx] = fmaf(fv, rv, m[dy * 9 + dx]);
        }
      }
    }
  }
  unsigned pm[3] = {0u, 0u, 0u}, nm[3] = {0u, 0u, 0u};
#pragma unroll
  for (int d = 0; d < 81; ++d) {
    float tg, vp, wm; consts_d(d, lwr, swr, mwr, tg, vp, wm);
    float s = m[d];
    float ga = vp * (s > 0.f ? 1.f : (s < 0.f ? wm : 0.5f * (1.f + wm)));
    m[d] = ga * fmaf(ga, s, -(vp * tg));
    pm[d / 27] |= (s > 0.f ? 1u : 0u) << (d % 27);
    nm[d / 27] |= (s < 0.f ? 1u : 0u) << (d % 27);
  }
  float t2[81];
#pragma unroll
  for (int d = 0; d < 81; ++d) t2[d] = 0.f;
  float num = 0.f;
  for (int c = 0; c < 256; ++c) {
    float fv = fb[(size_t)c * FPL];
    const float* rc = rb + (size_t)c * FPL;
    float g0 = 0.f, g1 = 0.f, g2 = 0.f, g3 = 0.f;
#pragma unroll
    for (int dy = 0; dy < 9; ++dy) {
      int yy = y + dy - 4;
      if ((unsigned)yy < 64u) {
        const float* rrow = rc + yy * 64;
#pragma unroll
        for (int dx = 0; dx < 9; ++dx) {
          int xx = x + dx - 4;
          float rv = ((unsigned)xx < 64u) ? rrow[xx] : 0.f;
          if ((dy & 3) == 0)      g0 = fmaf(m[dy * 9 + dx], rv, g0);
          else if ((dy & 3) == 1) g1 = fmaf(m[dy * 9 + dx], rv, g1);
          else if ((dy & 3) == 2) g2 = fmaf(m[dy * 9 + dx], rv, g2);
          else                    g3 = fmaf(m[dy * 9 + dx], rv, g3);
        }
      }
    }
    float g = fmaf(rw, fv, (g0 + g1) + (g2 + g3));
    num = fmaf(g, g, num);
#pragma unroll
    for (int dy = 0; dy < 9; ++dy) {
      int yy = y + dy - 4;
      if ((unsigned)yy < 64u) {
        const float* rrow = rc + yy * 64;
#pragma unroll
        for (int dx = 0; dx < 9; ++dx) {
          int xx = x + dx - 4;
          float rv = ((unsigned)xx < 64u) ? rrow[xx] : 0.f;
          t2[dy * 9 + dx] = fmaf(g, rv, t2[dy * 9 + dx]);
        }
      }
    }
  }
  float den = 0.f;
#pragma unroll
  for (int d = 0; d < 81; ++d) {
    float tg, vp, wm; consts_d(d, lwr, swr, mwr, tg, vp, wm);
    (void)tg;
    unsigned p = (pm[d / 27] >> (d % 27)) & 1u;
    unsigned n = (nm[d / 27] >> (d % 27)) & 1u;
    float ga = vp * (p ? 1.f : (n ? wm : 0.5f * (1.f + wm)));
    float s2 = ga * t2[d];
    den = fmaf(s2, s2, den);
  }
  den = fmaxf(fmaf(rw, num, den), 1e-8f);
  float coef = step * num / den;
  float* ob = fout + (size_t)b * 256 * FPL + (size_t)y * 64 + x;
  for (int c = 0; c < 256; ++c) {
    float fv = fb[(size_t)c * FPL];
    const float* rc = rb + (size_t)c * FPL;
    float g0 = 0.f, g1 = 0.f, g2 = 0.f, g3 = 0.f;
#pragma unroll
    for (int dy = 0; dy < 9; ++dy) {
      int yy = y + dy - 4;
      if ((unsigned)yy < 64u) {
        const float* rrow = rc + yy * 64;
#pragma unroll
        for (int dx = 0; dx < 9; ++dx) {
          int xx = x + dx - 4;
          float rv = ((unsigned)xx < 64u) ? rrow[xx] : 0.f;
          if ((dy & 3) == 0)      g0 = fmaf(m[dy * 9 + dx], rv, g0);
          else if ((dy & 3) == 1) g1 = fmaf(m[dy * 9 + dx], rv, g1);
          else if ((dy & 3) == 2) g2 = fmaf(m[dy * 9 + dx], rv, g2);
          else                    g3 = fmaf(m[dy * 9 + dx], rv, g3);
        }
      }
    }
    float g = fmaf(rw, fv, (g0 + g1) + (g2 + g3));
    ob[(size_t)c * FPL] = fmaf(-coef, g, fv);
  }
}

extern "C" void kernel_launch(void* const* d_in, const int* in_sizes, int n_in,
                              void* d_out, int out_size, void* d_ws, size_t ws_size,
                              hipStream_t stream) {
  (void)in_sizes; (void)n_in; (void)out_size;
  const float* f0 = (const float*)d_in[0];
  const float* r  = (const float*)d_in[1];
  const float* lsl = (const float*)d_in[2];
  const float* freg = (const float*)d_in[3];
  const float* lw = (const float*)d_in[4];
  const float* sw = (const float*)d_in[5];
  const float* mw = (const float*)d_in[6];
  float* out = (float*)d_out;

  const size_t CONSTS = 256;
  const size_t GSZ = (size_t)16 * 256 * 64 * 64;     // gbuf floats
  const size_t RPSZ = (size_t)16 * 64 * 72 * 72 * 4; // rpad floats
  const size_t needed = (CONSTS + GSZ + RPSZ) * sizeof(float);

  if (ws_size >= needed) {
    float* ws = (float*)d_ws;
    float* gbuf = ws + CONSTS;
    float* rpad = gbuf + GSZ;
    k_consts<<<dim3(1), dim3(128), 0, stream>>>(lsl, freg, lw, sw, mw, ws);
    k_pad<<<dim3((unsigned)((RPSZ + 255) / 256)), dim3(256), 0, stream>>>(r, rpad);
    k_iterB<<<dim3(1024), dim3(256), 0, stream>>>(f0, rpad, ws, gbuf, out);
    k_iterB<<<dim3(1024), dim3(256), 0, stream>>>(out, rpad, ws, gbuf, out);
    k_iterB<<<dim3(1024), dim3(256), 0, stream>>>(out, rpad, ws, gbuf, out);
  } else {
    k_iterC<<<dim3(1024), dim3(64), 0, stream>>>(f0, r, lsl, freg, lw, sw, mw, out);
    k_iterC<<<dim3(1024), dim3(64), 0, stream>>>(out, r, lsl, freg, lw, sw, mw, out);
    k_iterC<<<dim3(1024), dim3(64), 0, stream>>>(out, r, lsl, freg, lw, sw, mw, out);
  }
}

// Round 7
// 1815.508 us; speedup vs baseline: 2.1519x; 1.5928x over previous
//
#include <hip/hip_runtime.h>
#include <cstddef>

// LocalGOCorrOpt on MI355X — round 7: resubmit of rounds 5/6 (two GPU
// acquisition timeouts; never measured). d-split decomposition to kill the
// round-4 spill:
//   - wave w owns d-slots: dy rows {2w,2w+1} (18) + slice of row 8 (3/2/2/2)
//     -> 21/20/20/20 accumulators; P1/P3b reduction-free (all channels/wave).
//   - mapped[81][64] lives in LDS (smat), consumed by channel-split P3a.
//   - masks: 21 bits/thread; den computed per-wave over own d's.
// Live set ~70-90 VGPR -> launch_bounds(256,4): 16 waves/CU, no scratch.

#define FPL 4096   // 64*64 floats per f channel-plane
#define RPQ 20736  // 72*72*4 floats per rpad c4-plane
#define GPQ 16384  // 64*64*4 floats per gbuf c4-plane

// ---------------- constants kernel ----------------
__global__ void k_consts(const float* lsl, const float* freg, const float* lw,
                         const float* sw, const float* mw, float* ws) {
  int t = threadIdx.x;
  if (t < 81) {
    int dy = t / 9, dx = t % 9;
    float ky = (float)(dy - 4), kx = (float)(dx - 4);
    float dist = sqrtf(ky * ky + kx * kx);
    float tg = 0.f, vp = 0.f, z = 0.f;
    for (int k = 0; k < 10; ++k) {
      float bd = 2.f * dist - (float)k;               // dist/0.5 - k
      float bin = (k < 9) ? fmaxf(1.f - fabsf(bd), 0.f)
                          : fminf(fmaxf(1.f + bd, 0.f), 1.f);
      tg += lw[k] * bin; vp += sw[k] * bin; z += mw[k] * bin;
    }
    ws[t] = tg;                      // target_map
    ws[81 + t] = vp;                 // v_plus
    ws[162 + t] = 1.f / (1.f + expf(-z));  // weight_m (sigmoid)
  } else if (t == 81) {
    float fr = freg[0];
    ws[243] = fmaxf(fr * fr, 1e-10f) * (1.f / 65536.f);  // reg_weight
  } else if (t == 82) {
    ws[244] = expf(lsl[0]);          // step_length
  }
}

// ---------------- r repack: NCHW -> padded channel-quad ----------------
__global__ void k_pad(const float* __restrict__ r, float* __restrict__ rp) {
  size_t i = (size_t)blockIdx.x * 256 + threadIdx.x;
  const size_t N = (size_t)16 * 64 * 72 * 72 * 4;
  if (i >= N) return;
  int j = (int)(i & 3);
  size_t qi = i >> 2;
  int col = (int)(qi % 72); size_t t1 = qi / 72;
  int row = (int)(t1 % 72); size_t t2 = t1 / 72;
  int c4 = (int)(t2 % 64);  int b  = (int)(t2 / 64);
  int yy = row - 4, xx = col - 4;
  float v = 0.f;
  if ((unsigned)yy < 64u && (unsigned)xx < 64u)
    v = r[(((size_t)b * 256 + (size_t)(c4 * 4 + j)) * 64 + yy) * 64 + xx];
  rp[i] = v;
}

// ---------------- fused single-iteration kernel (d-split) ----------------
__global__ __launch_bounds__(256, 4) void k_iterD(
    const float* fin, const float* __restrict__ rp,
    const float* __restrict__ cst, float* __restrict__ gbuf, float* fout) {
  // XCD-bijective swizzle: 1024 workgroups % 8 == 0.
  const int wg = blockIdx.x;
  const int swz = (wg & 7) * 128 + (wg >> 3);
  const int b = swz >> 6, y = swz & 63;
  const int tid = threadIdx.x;
  const int w = tid >> 6;          // wave 0..3
  const int x = tid & 63;          // pixel column
  const float rw = cst[243], step = cst[244];

  // d ownership: rows DYA, DYA+1 (18 slots) + row 8 cols [DX8, DX8+NX8)
  const int DYA = 2 * w;
  const int DX8 = (w == 0) ? 0 : (1 + 2 * w);    // 0,3,5,7
  const int NX8 = (w == 0) ? 3 : 2;

  const float* fbase = fin + (size_t)b * 256 * FPL + (size_t)y * 64 + x;
  const float* rbase = rp + (size_t)b * 64 * RPQ + ((size_t)y * 72 + x) * 4;
  float* gb = gbuf + (size_t)b * 64 * GPQ + ((size_t)y * 64 + x) * 4;

  __shared__ float smat[81][64];   // mapped matrix; lane-stride-1 -> no conflicts
  __shared__ float nbuf[4][64];
  __shared__ float dbuf[4][64];

  // ---- P1: scores for own d-slots over ALL channels ----
  float acc[2][9], acc8[3];
#pragma unroll
  for (int i = 0; i < 2; ++i)
#pragma unroll
    for (int dx = 0; dx < 9; ++dx) acc[i][dx] = 0.f;
#pragma unroll
  for (int k = 0; k < 3; ++k) acc8[k] = 0.f;

  for (int c4 = 0; c4 < 64; ++c4) {
    const float* fc = fbase + (size_t)c4 * 4 * FPL;
    float f0 = fc[0], f1 = fc[FPL], f2 = fc[2 * FPL], f3 = fc[3 * FPL];
    const float* rc = rbase + (size_t)c4 * RPQ;
#pragma unroll
    for (int i = 0; i < 2; ++i) {
      const float* rrow = rc + (size_t)(DYA + i) * 288;   // 72*4 floats per row
#pragma unroll
      for (int dx = 0; dx < 9; ++dx) {
        float4 rv = *(const float4*)(rrow + dx * 4);
        float a = acc[i][dx];
        a = fmaf(f0, rv.x, a); a = fmaf(f1, rv.y, a);
        a = fmaf(f2, rv.z, a); a = fmaf(f3, rv.w, a);
        acc[i][dx] = a;
      }
    }
    {
      const float* rrow = rc + 8 * 288 + (size_t)DX8 * 4;
#pragma unroll
      for (int k = 0; k < 3; ++k) {
        if (k < NX8) {
          float4 rv = *(const float4*)(rrow + k * 4);
          float a = acc8[k];
          a = fmaf(f0, rv.x, a); a = fmaf(f1, rv.y, a);
          a = fmaf(f2, rv.z, a); a = fmaf(f3, rv.w, a);
          acc8[k] = a;
        }
      }
    }
  }

  // ---- P2: mapped for own d's -> smat; sign bits in one mask ----
  unsigned pmask = 0u, nmask = 0u;
#pragma unroll
  for (int i = 0; i < 2; ++i) {
#pragma unroll
    for (int dx = 0; dx < 9; ++dx) {
      int d = (DYA + i) * 9 + dx;
      float s = acc[i][dx];
      float tg = cst[d], vp = cst[81 + d], wm = cst[162 + d];
      float ga = vp * (s > 0.f ? 1.f : (s < 0.f ? wm : 0.5f * (1.f + wm)));
      smat[d][x] = ga * fmaf(ga, s, -(vp * tg));
      pmask |= (s > 0.f ? 1u : 0u) << (i * 9 + dx);
      nmask |= (s < 0.f ? 1u : 0u) << (i * 9 + dx);
    }
  }
#pragma unroll
  for (int k = 0; k < 3; ++k) {
    if (k < NX8) {
      int d = 72 + DX8 + k;
      float s = acc8[k];
      float tg = cst[d], vp = cst[81 + d], wm = cst[162 + d];
      float ga = vp * (s > 0.f ? 1.f : (s < 0.f ? wm : 0.5f * (1.f + wm)));
      smat[d][x] = ga * fmaf(ga, s, -(vp * tg));
      pmask |= (s > 0.f ? 1u : 0u) << (18 + k);
      nmask |= (s < 0.f ? 1u : 0u) << (18 + k);
    }
  }
  __syncthreads();

  // ---- P3a: g = rw*f + R*mapped, channel-split (16 c4 per wave, chunks of 4) ----
  const int c4lo = w * 16;
  float npart = 0.f;
  for (int cc = 0; cc < 4; ++cc) {
    const int c4a = c4lo + cc * 4;
    float g[4][4];
#pragma unroll
    for (int q = 0; q < 4; ++q)
#pragma unroll
      for (int j = 0; j < 4; ++j) g[q][j] = 0.f;

    for (int dy = 0; dy < 9; ++dy) {
      float m[9];
#pragma unroll
      for (int dx = 0; dx < 9; ++dx) m[dx] = smat[dy * 9 + dx][x];
#pragma unroll
      for (int q = 0; q < 4; ++q) {
        const float* rrow = rbase + (size_t)(c4a + q) * RPQ + (size_t)dy * 288;
#pragma unroll
        for (int dx = 0; dx < 9; ++dx) {
          float4 rv = *(const float4*)(rrow + dx * 4);
          g[q][0] = fmaf(m[dx], rv.x, g[q][0]);
          g[q][1] = fmaf(m[dx], rv.y, g[q][1]);
          g[q][2] = fmaf(m[dx], rv.z, g[q][2]);
          g[q][3] = fmaf(m[dx], rv.w, g[q][3]);
        }
      }
    }
#pragma unroll
    for (int q = 0; q < 4; ++q) {
      const float* fc = fbase + (size_t)(c4a + q) * 4 * FPL;
      float4 g4;
      g4.x = fmaf(rw, fc[0],           g[q][0]);
      g4.y = fmaf(rw, fc[FPL],         g[q][1]);
      g4.z = fmaf(rw, fc[2 * FPL],     g[q][2]);
      g4.w = fmaf(rw, fc[3 * FPL],     g[q][3]);
      *(float4*)(gb + (size_t)(c4a + q) * GPQ) = g4;
      npart = fmaf(g4.x, g4.x, npart); npart = fmaf(g4.y, g4.y, npart);
      npart = fmaf(g4.z, g4.z, npart); npart = fmaf(g4.w, g4.w, npart);
    }
  }
  nbuf[w][x] = npart;
  __syncthreads();   // gbuf writes drained; nbuf visible

  // ---- P3b: t2 for own d-slots over ALL channels (reuse acc) ----
#pragma unroll
  for (int i = 0; i < 2; ++i)
#pragma unroll
    for (int dx = 0; dx < 9; ++dx) acc[i][dx] = 0.f;
#pragma unroll
  for (int k = 0; k < 3; ++k) acc8[k] = 0.f;

  for (int c4 = 0; c4 < 64; ++c4) {
    float4 gq = *(const float4*)(gb + (size_t)c4 * GPQ);
    const float* rc = rbase + (size_t)c4 * RPQ;
#pragma unroll
    for (int i = 0; i < 2; ++i) {
      const float* rrow = rc + (size_t)(DYA + i) * 288;
#pragma unroll
      for (int dx = 0; dx < 9; ++dx) {
        float4 rv = *(const float4*)(rrow + dx * 4);
        float a = acc[i][dx];
        a = fmaf(gq.x, rv.x, a); a = fmaf(gq.y, rv.y, a);
        a = fmaf(gq.z, rv.z, a); a = fmaf(gq.w, rv.w, a);
        acc[i][dx] = a;
      }
    }
    {
      const float* rrow = rc + 8 * 288 + (size_t)DX8 * 4;
#pragma unroll
      for (int k = 0; k < 3; ++k) {
        if (k < NX8) {
          float4 rv = *(const float4*)(rrow + k * 4);
          float a = acc8[k];
          a = fmaf(gq.x, rv.x, a); a = fmaf(gq.y, rv.y, a);
          a = fmaf(gq.z, rv.z, a); a = fmaf(gq.w, rv.w, a);
          acc8[k] = a;
        }
      }
    }
  }

  // ---- P4: den partial over own d's ----
  float dpart = 0.f;
#pragma unroll
  for (int i = 0; i < 2; ++i) {
#pragma unroll
    for (int dx = 0; dx < 9; ++dx) {
      int d = (DYA + i) * 9 + dx;
      float vp = cst[81 + d], wm = cst[162 + d];
      unsigned p = (pmask >> (i * 9 + dx)) & 1u;
      unsigned n = (nmask >> (i * 9 + dx)) & 1u;
      float ga = vp * (p ? 1.f : (n ? wm : 0.5f * (1.f + wm)));
      float s2 = ga * acc[i][dx];
      dpart = fmaf(s2, s2, dpart);
    }
  }
#pragma unroll
  for (int k = 0; k < 3; ++k) {
    if (k < NX8) {
      int d = 72 + DX8 + k;
      float vp = cst[81 + d], wm = cst[162 + d];
      unsigned p = (pmask >> (18 + k)) & 1u;
      unsigned n = (nmask >> (18 + k)) & 1u;
      float ga = vp * (p ? 1.f : (n ? wm : 0.5f * (1.f + wm)));
      float s2 = ga * acc8[k];
      dpart = fmaf(s2, s2, dpart);
    }
  }
  dbuf[w][x] = dpart;
  __syncthreads();

  const float num = (nbuf[0][x] + nbuf[1][x]) + (nbuf[2][x] + nbuf[3][x]);
  float den = (dbuf[0][x] + dbuf[1][x]) + (dbuf[2][x] + dbuf[3][x]);
  den = fmaxf(fmaf(rw, num, den), 1e-8f);
  const float coef = step * num / den;

  // ---- P5: f_new = f - coef*g, channel-split ----
  float* ob = fout + (size_t)b * 256 * FPL + (size_t)y * 64 + x;
  for (int c4 = c4lo; c4 < c4lo + 16; ++c4) {
    const float* fc = fbase + (size_t)c4 * 4 * FPL;
    float4 g4 = *(const float4*)(gb + (size_t)c4 * GPQ);
    size_t o = (size_t)c4 * 4 * FPL;
    ob[o]           = fmaf(-coef, g4.x, fc[0]);
    ob[o + FPL]     = fmaf(-coef, g4.y, fc[FPL]);
    ob[o + 2 * FPL] = fmaf(-coef, g4.z, fc[2 * FPL]);
    ob[o + 3 * FPL] = fmaf(-coef, g4.w, fc[3 * FPL]);
  }
}

// ---------------- fallback: self-contained, no workspace needed ----------------
__device__ __forceinline__ void consts_d(int d, const float* lwr, const float* swr,
                                         const float* mwr, float& tg, float& vp,
                                         float& wm) {
  int dy = d / 9, dx = d % 9;
  float ky = (float)(dy - 4), kx = (float)(dx - 4);
  float dist = sqrtf(ky * ky + kx * kx);
  float t = 0.f, v = 0.f, z = 0.f;
#pragma unroll
  for (int k = 0; k < 10; ++k) {
    float bd = 2.f * dist - (float)k;
    float bin = (k < 9) ? fmaxf(1.f - fabsf(bd), 0.f)
                        : fminf(fmaxf(1.f + bd, 0.f), 1.f);
    t = fmaf(lwr[k], bin, t); v = fmaf(swr[k], bin, v); z = fmaf(mwr[k], bin, z);
  }
  tg = t; vp = v; wm = 1.f / (1.f + expf(-z));
}

__global__ __launch_bounds__(64, 1) void k_iterC(
    const float* fin, const float* __restrict__ r, const float* __restrict__ lsl,
    const float* __restrict__ freg, const float* __restrict__ lw,
    const float* __restrict__ sw, const float* __restrict__ mw, float* fout) {
  const int b = blockIdx.x >> 6, y = blockIdx.x & 63;
  const int x = threadIdx.x;
  float lwr[10], swr[10], mwr[10];
#pragma unroll
  for (int k = 0; k < 10; ++k) { lwr[k] = lw[k]; swr[k] = sw[k]; mwr[k] = mw[k]; }
  float fr = freg[0];
  const float rw = fmaxf(fr * fr, 1e-10f) * (1.f / 65536.f);
  const float step = expf(lsl[0]);
  const float* fb = fin + (size_t)b * 256 * FPL + (size_t)y * 64 + x;
  const float* rb = r + (size_t)b * 256 * FPL;

  float m[81];
#pragma unroll
  for (int d = 0; d < 81; ++d) m[d] = 0.f;
  for (int c = 0; c < 256; ++c) {
    float fv = fb[(size_t)c * FPL];
    const float* rc = rb + (size_t)c * FPL;
#pragma unroll
    for (int dy = 0; dy < 9; ++dy) {
      int yy = y + dy - 4;
      if ((unsigned)yy < 64u) {
        const float* rrow = rc + yy * 64;
#pragma unroll
        for (int dx = 0; dx < 9; ++dx) {
          int xx = x + dx - 4;
          float rv = ((unsigned)xx < 64u) ? rrow[xx] : 0.f;
          m[dy * 9 + dx] = fmaf(fv, rv, m[dy * 9 + dx]);
        }
      }
    }
  }
  unsigned pm[3] = {0u, 0u, 0u}, nm[3] = {0u, 0u, 0u};
#pragma unroll
  for (int d = 0; d < 81; ++d) {
    float tg, vp, wm; consts_d(d, lwr, swr, mwr, tg, vp, wm);
    float s = m[d];
    float ga = vp * (s > 0.f ? 1.f : (s < 0.f ? wm : 0.5f * (1.f + wm)));
    m[d] = ga * fmaf(ga, s, -(vp * tg));
    pm[d / 27] |= (s > 0.f ? 1u : 0u) << (d % 27);
    nm[d / 27] |= (s < 0.f ? 1u : 0u) << (d % 27);
  }
  float t2[81];
#pragma unroll
  for (int d = 0; d < 81; ++d) t2[d] = 0.f;
  float num = 0.f;
  for (int c = 0; c < 256; ++c) {
    float fv = fb[(size_t)c * FPL];
    const float* rc = rb + (size_t)c * FPL;
    float g0 = 0.f, g1 = 0.f, g2 = 0.f, g3 = 0.f;
#pragma unroll
    for (int dy = 0; dy < 9; ++dy) {
      int yy = y + dy - 4;
      if ((unsigned)yy < 64u) {
        const float* rrow = rc + yy * 64;
#pragma unroll
        for (int dx = 0; dx < 9; ++dx) {
          int xx = x + dx - 4;
          float rv = ((unsigned)xx < 64u) ? rrow[xx] : 0.f;
          if ((dy & 3) == 0)      g0 = fmaf(m[dy * 9 + dx], rv, g0);
          else if ((dy & 3) == 1) g1 = fmaf(m[dy * 9 + dx], rv, g1);
          else if ((dy & 3) == 2) g2 = fmaf(m[dy * 9 + dx], rv, g2);
          else                    g3 = fmaf(m[dy * 9 + dx], rv, g3);
        }
      }
    }
    float g = fmaf(rw, fv, (g0 + g1) + (g2 + g3));
    num = fmaf(g, g, num);
#pragma unroll
    for (int dy = 0; dy < 9; ++dy) {
      int yy = y + dy - 4;
      if ((unsigned)yy < 64u) {
        const float* rrow = rc + yy * 64;
#pragma unroll
        for (int dx = 0; dx < 9; ++dx) {
          int xx = x + dx - 4;
          float rv = ((unsigned)xx < 64u) ? rrow[xx] : 0.f;
          t2[dy * 9 + dx] = fmaf(g, rv, t2[dy * 9 + dx]);
        }
      }
    }
  }
  float den = 0.f;
#pragma unroll
  for (int d = 0; d < 81; ++d) {
    float tg, vp, wm; consts_d(d, lwr, swr, mwr, tg, vp, wm);
    (void)tg;
    unsigned p = (pm[d / 27] >> (d % 27)) & 1u;
    unsigned n = (nm[d / 27] >> (d % 27)) & 1u;
    float ga = vp * (p ? 1.f : (n ? wm : 0.5f * (1.f + wm)));
    float s2 = ga * t2[d];
    den = fmaf(s2, s2, den);
  }
  den = fmaxf(fmaf(rw, num, den), 1e-8f);
  float coef = step * num / den;
  float* ob = fout + (size_t)b * 256 * FPL + (size_t)y * 64 + x;
  for (int c = 0; c < 256; ++c) {
    float fv = fb[(size_t)c * FPL];
    const float* rc = rb + (size_t)c * FPL;
    float g0 = 0.f, g1 = 0.f, g2 = 0.f, g3 = 0.f;
#pragma unroll
    for (int dy = 0; dy < 9; ++dy) {
      int yy = y + dy - 4;
      if ((unsigned)yy < 64u) {
        const float* rrow = rc + yy * 64;
#pragma unroll
        for (int dx = 0; dx < 9; ++dx) {
          int xx = x + dx - 4;
          float rv = ((unsigned)xx < 64u) ? rrow[xx] : 0.f;
          if ((dy & 3) == 0)      g0 = fmaf(m[dy * 9 + dx], rv, g0);
          else if ((dy & 3) == 1) g1 = fmaf(m[dy * 9 + dx], rv, g1);
          else if ((dy & 3) == 2) g2 = fmaf(m[dy * 9 + dx], rv, g2);
          else                    g3 = fmaf(m[dy * 9 + dx], rv, g3);
        }
      }
    }
    float g = fmaf(rw, fv, (g0 + g1) + (g2 + g3));
    ob[(size_t)c * FPL] = fmaf(-coef, g, fv);
  }
}

extern "C" void kernel_launch(void* const* d_in, const int* in_sizes, int n_in,
                              void* d_out, int out_size, void* d_ws, size_t ws_size,
                              hipStream_t stream) {
  (void)in_sizes; (void)n_in; (void)out_size;
  const float* f0 = (const float*)d_in[0];
  const float* r  = (const float*)d_in[1];
  const float* lsl = (const float*)d_in[2];
  const float* freg = (const float*)d_in[3];
  const float* lw = (const float*)d_in[4];
  const float* sw = (const float*)d_in[5];
  const float* mw = (const float*)d_in[6];
  float* out = (float*)d_out;

  const size_t CONSTS = 256;
  const size_t GSZ = (size_t)16 * 256 * 64 * 64;     // gbuf floats
  const size_t RPSZ = (size_t)16 * 64 * 72 * 72 * 4; // rpad floats
  const size_t needed = (CONSTS + GSZ + RPSZ) * sizeof(float);

  if (ws_size >= needed) {
    float* ws = (float*)d_ws;
    float* gbuf = ws + CONSTS;
    float* rpad = gbuf + GSZ;
    k_consts<<<dim3(1), dim3(128), 0, stream>>>(lsl, freg, lw, sw, mw, ws);
    k_pad<<<dim3((unsigned)((RPSZ + 255) / 256)), dim3(256), 0, stream>>>(r, rpad);
    k_iterD<<<dim3(1024), dim3(256), 0, stream>>>(f0, rpad, ws, gbuf, out);
    k_iterD<<<dim3(1024), dim3(256), 0, stream>>>(out, rpad, ws, gbuf, out);
    k_iterD<<<dim3(1024), dim3(256), 0, stream>>>(out, rpad, ws, gbuf, out);
  } else {
    k_iterC<<<dim3(1024), dim3(64), 0, stream>>>(f0, r, lsl, freg, lw, sw, mw, out);
    k_iterC<<<dim3(1024), dim3(64), 0, stream>>>(out, r, lsl, freg, lw, sw, mw, out);
    k_iterC<<<dim3(1024), dim3(64), 0, stream>>>(out, r, lsl, freg, lw, sw, mw, out);
  }
}